// Round 1
// baseline (887.171 us; speedup 1.0000x reference)
//
#include <hip/hip_runtime.h>
#include <stdint.h>
#include <stddef.h>

// ---------------- problem constants ----------------
#define S_LEN 2048
#define HIDN  2048
#define HQ    16
#define HKV   4
#define HDIM  128
#define NQKV  3072      // HQ*D + 2*HKV*D
#define QBLK  32        // S/64
#define GHW   128
#define INTER 5632
#define NEGF  (-1e30f)
#define THRG  0.004f

typedef short bf16x8 __attribute__((ext_vector_type(8)));
typedef float f32x4  __attribute__((ext_vector_type(4)));

__device__ __forceinline__ short f2bf(float f) {
  union { float f; unsigned u; } v; v.f = f;
  unsigned r = (v.u + 0x7FFFu + ((v.u >> 16) & 1u)) >> 16;
  return (short)r;
}
__device__ __forceinline__ float bf2f(short s) {
  union { float f; unsigned u; } v; v.u = ((unsigned)(unsigned short)s) << 16;
  return v.f;
}
__device__ __forceinline__ void gload16(const void* g, void* l) {
  __builtin_amdgcn_global_load_lds(
      (const __attribute__((address_space(1))) void*)g,
      (__attribute__((address_space(3))) void*)l, 16, 0, 0);
}

// ---------------- transpose + cast fp32 (R x C) -> bf16 (C x R) ----------------
__global__ __launch_bounds__(256) void k_transpose_cast(
    const float* __restrict__ src, short* __restrict__ dst, int R, int C) {
  __shared__ float t[32][33];
  const int tx = threadIdx.x, ty = threadIdx.y;
  const int x = blockIdx.x * 32 + tx;
  const int y0 = blockIdx.y * 32;
#pragma unroll
  for (int i = 0; i < 4; i++) {
    int yy = ty + i * 8;
    t[yy][tx] = src[(long)(y0 + yy) * C + x];
  }
  __syncthreads();
  const int xo = blockIdx.y * 32 + tx;
  const int yo0 = blockIdx.x * 32;
#pragma unroll
  for (int i = 0; i < 4; i++) {
    int yy = ty + i * 8;
    dst[(long)(yo0 + yy) * R + xo] = f2bf(t[tx][yy]);
  }
}

// ---------------- concat qkv bias ----------------
__global__ void k_bias_concat(const float* __restrict__ bq, const float* __restrict__ bk,
                              const float* __restrict__ bv, float* __restrict__ out) {
  int i = blockIdx.x * 256 + threadIdx.x;
  if (i < 2048) out[i] = bq[i];
  else if (i < 2560) out[i] = bk[i - 2048];
  else out[i] = bv[i - 2560];
}

// ---------------- RMSNorm fp32 -> bf16 ----------------
__global__ __launch_bounds__(256) void k_rms(const float* __restrict__ x,
                                             const float* __restrict__ w,
                                             short* __restrict__ out) {
  const int row = blockIdx.x;
  const float* xr = x + (long)row * HIDN;
  float v[8];
  float ss = 0.f;
#pragma unroll
  for (int i = 0; i < 8; i++) {
    v[i] = xr[threadIdx.x + i * 256];
    ss += v[i] * v[i];
  }
#pragma unroll
  for (int off = 32; off > 0; off >>= 1) ss += __shfl_down(ss, off, 64);
  __shared__ float red[4];
  const int wave = threadIdx.x >> 6, lane = threadIdx.x & 63;
  if (lane == 0) red[wave] = ss;
  __syncthreads();
  float tot = red[0] + red[1] + red[2] + red[3];
  float rs = rsqrtf(tot / (float)HIDN + 1e-6f);
#pragma unroll
  for (int i = 0; i < 8; i++) {
    int c = threadIdx.x + i * 256;
    out[(long)row * HIDN + c] = f2bf(v[i] * rs * w[c]);
  }
}

// ---------------- GEMM: C[M,N] = A[M,K](bf16) * Bt[N,K](bf16)^T  ----------------
// MODE 0: Cf = acc + bias? + add?   (fp32 out)
// MODE 1: Cb = bf16(acc)
// MODE 2: Cb = bf16(silu(gaux) * acc)
template <int MODE>
__global__ __launch_bounds__(256) void k_gemm(
    const short* __restrict__ A, const short* __restrict__ Bt,
    float* __restrict__ Cf, short* __restrict__ Cb,
    const float* __restrict__ bias, const float* __restrict__ add,
    const short* __restrict__ gaux, int M, int N, int K) {
  __shared__ short As[128 * 32];
  __shared__ short Bs[128 * 32];
  const int tid = threadIdx.x;
  const int wave = tid >> 6, lane = tid & 63, quad = lane >> 4, l15 = lane & 15;
  const long m0 = (long)blockIdx.y * 128, n0 = (long)blockIdx.x * 128;
  const int wr = (wave >> 1) * 64, wc = (wave & 1) * 64;
  f32x4 acc[4][4] = {};
  const int r4 = tid >> 2, c8 = (tid & 3) * 8;
  const short* Ag0 = A + (m0 + r4) * K + c8;
  const short* Ag1 = A + (m0 + 64 + r4) * K + c8;
  const short* Bg0 = Bt + (n0 + r4) * K + c8;
  const short* Bg1 = Bt + (n0 + 64 + r4) * K + c8;
  short* AsW0 = &As[wave * 512];
  short* AsW1 = &As[2048 + wave * 512];
  short* BsW0 = &Bs[wave * 512];
  short* BsW1 = &Bs[2048 + wave * 512];
  for (int k0 = 0; k0 < K; k0 += 32) {
    __syncthreads();
    gload16(Ag0 + k0, AsW0);
    gload16(Ag1 + k0, AsW1);
    gload16(Bg0 + k0, BsW0);
    gload16(Bg1 + k0, BsW1);
    __syncthreads();
    bf16x8 af[4], bb[4];
#pragma unroll
    for (int mi = 0; mi < 4; mi++)
      af[mi] = *(const bf16x8*)&As[(wr + mi * 16 + l15) * 32 + quad * 8];
#pragma unroll
    for (int ni = 0; ni < 4; ni++)
      bb[ni] = *(const bf16x8*)&Bs[(wc + ni * 16 + l15) * 32 + quad * 8];
#pragma unroll
    for (int mi = 0; mi < 4; mi++)
#pragma unroll
      for (int ni = 0; ni < 4; ni++)
        acc[mi][ni] = __builtin_amdgcn_mfma_f32_16x16x32_bf16(af[mi], bb[ni], acc[mi][ni], 0, 0, 0);
  }
  const bool hb = (MODE == 0) && (bias != nullptr);
  const bool ha = (MODE == 0) && (add != nullptr);
#pragma unroll
  for (int mi = 0; mi < 4; mi++) {
#pragma unroll
    for (int ni = 0; ni < 4; ni++) {
      long mbase = m0 + wr + mi * 16 + quad * 4;
      long n = n0 + wc + ni * 16 + l15;
#pragma unroll
      for (int r = 0; r < 4; r++) {
        float v = acc[mi][ni][r];
        long idx = (mbase + r) * N + n;
        if (MODE == 0) {
          if (hb) v += bias[n];
          if (ha) v += add[idx];
          Cf[idx] = v;
        } else if (MODE == 1) {
          Cb[idx] = f2bf(v);
        } else {
          float g = bf2f(gaux[idx]);
          float sg = g / (1.f + __expf(-g));
          Cb[idx] = f2bf(sg * v);
        }
      }
    }
  }
}

// ---------------- block means of q and k (pre-RoPE) ----------------
__global__ __launch_bounds__(256) void k_blockmean(const float* __restrict__ qkv,
                                                   float* __restrict__ qm,
                                                   float* __restrict__ km) {
  int id = blockIdx.x * 256 + threadIdx.x;  // 32 * 2560
  int qb = id / 2560, c = id % 2560;        // cols 0..2559 = q(2048) + k(512)
  const float* base = qkv + (long)qb * 64 * NQKV + c;
  float acc = 0.f;
  for (int s = 0; s < 64; s++) acc += base[(long)s * NQKV];
  acc *= (1.f / 64.f);
  if (c < 2048) qm[(long)qb * 2048 + c] = acc;
  else km[(long)qb * 512 + (c - 2048)] = acc;
}

// ---------------- gate projections qg = qm@gWq, kg = km@gWk ----------------
__global__ __launch_bounds__(128) void k_gateproj(const float* __restrict__ qm,
                                                  const float* __restrict__ km,
                                                  const float* __restrict__ gWq,
                                                  const float* __restrict__ gWk,
                                                  float* __restrict__ qg,
                                                  float* __restrict__ kg) {
  __shared__ float xm[128];
  const int b = blockIdx.x;
  const float* src; const float* W; float* dst;
  if (b < 512) { src = qm + (long)b * 128; W = gWq; dst = qg + (long)b * 128; }
  else { int r = b - 512; src = km + (long)r * 128; W = gWk; dst = kg + (long)r * 128; }
  xm[threadIdx.x] = src[threadIdx.x];
  __syncthreads();
  float acc = 0.f;
  for (int d = 0; d < 128; d++) acc += xm[d] * W[d * GHW + threadIdx.x];
  dst[threadIdx.x] = acc;
}

// ---------------- gate softmax + keep mask ----------------
__global__ __launch_bounds__(64) void k_gatemask(const float* __restrict__ qg,
                                                 const float* __restrict__ kg,
                                                 unsigned char* __restrict__ mask) {
  const int qb = blockIdx.x, h = blockIdx.y;
  __shared__ float qv[128];
  const int t = threadIdx.x;
  qv[t] = qg[((long)qb * 16 + h) * 128 + t];
  qv[t + 64] = qg[((long)qb * 16 + h) * 128 + t + 64];
  __syncthreads();
  const int kb = t;
  float s = NEGF;
  if (kb < 32 && kb <= qb) {
    const float* kr = kg + ((long)kb * 4 + (h >> 2)) * 128;
    float acc = 0.f;
    for (int d = 0; d < 128; d++) acc += qv[d] * kr[d];
    s = acc * 0.08838834764831845f;  // GH^-0.5
  }
  float m = s;
#pragma unroll
  for (int off = 32; off > 0; off >>= 1) m = fmaxf(m, __shfl_xor(m, off, 64));
  float e = (kb < 32 && kb <= qb) ? __expf(s - m) : 0.f;
  float sum = e;
#pragma unroll
  for (int off = 32; off > 0; off >>= 1) sum += __shfl_xor(sum, off, 64);
  if (kb < 32) {
    float gate = e / sum;
    bool keep = (kb <= qb) && (gate >= THRG || kb == qb);
    mask[((long)h * 32 + qb) * 32 + kb] = keep ? 1 : 0;
  }
}

// ---------------- RoPE + cast q,k -> head-major bf16 ----------------
__global__ __launch_bounds__(256) void k_rope(const float* __restrict__ qkv,
                                              const float* __restrict__ cosb,
                                              const float* __restrict__ sinb,
                                              short* __restrict__ q_bf,
                                              short* __restrict__ k_bf) {
  long id = (long)blockIdx.x * 256 + threadIdx.x;  // S * 20 * 64
  int d = (int)(id & 63);
  long rest = id >> 6;
  int head = (int)(rest % 20);
  int s = (int)(rest / 20);
  const float c = cosb[(long)s * HDIM + d];
  const float sn = sinb[(long)s * HDIM + d];
  if (head < HQ) {
    const float* src = qkv + (long)s * NQKV + head * HDIM;
    float x1 = src[d], x2 = src[d + 64];
    short* dst = q_bf + ((long)head * S_LEN + s) * HDIM;
    dst[d] = f2bf(x1 * c - x2 * sn);
    dst[d + 64] = f2bf(x2 * c + x1 * sn);
  } else {
    int hk = head - HQ;
    const float* src = qkv + (long)s * NQKV + 2048 + hk * HDIM;
    float x1 = src[d], x2 = src[d + 64];
    short* dst = k_bf + ((long)hk * S_LEN + s) * HDIM;
    dst[d] = f2bf(x1 * c - x2 * sn);
    dst[d + 64] = f2bf(x2 * c + x1 * sn);
  }
}

// ---------------- v transpose-cast: v_t[hk][d][s] ----------------
__global__ __launch_bounds__(256) void k_vcast(const float* __restrict__ qkv,
                                               short* __restrict__ v_t) {
  long id = (long)blockIdx.x * 256 + threadIdx.x;  // HKV*HDIM*S
  int s = (int)(id & (S_LEN - 1));
  long rest = id >> 11;
  int d = (int)(rest & 127);
  int hk = (int)(rest >> 7);
  v_t[id] = f2bf(qkv[(long)s * NQKV + 2560 + hk * HDIM + d]);
}

// ---------------- flash attention with block mask ----------------
__global__ __launch_bounds__(256) void k_attn(const short* __restrict__ q_bf,
                                              const short* __restrict__ k_bf,
                                              const short* __restrict__ v_t,
                                              const unsigned char* __restrict__ mask,
                                              short* __restrict__ o_bf) {
  const int qb = blockIdx.x, h = blockIdx.y;
  const int tid = threadIdx.x, wave = tid >> 6, lane = tid & 63;
  const int quad = lane >> 4, l15 = lane & 15;
  __shared__ short Qs[64 * 128];
  __shared__ short Ks[64 * 128];
  __shared__ short Vs[128 * 64];
  __shared__ short Ps[4 * 16 * 64];
  {
    const short* src = q_bf + ((long)h * S_LEN + (long)qb * 64) * HDIM;
#pragma unroll
    for (int i = 0; i < 4; i++) {
      int flat = tid + i * 256;
      gload16(src + (long)flat * 8, &Qs[(i * 256 + wave * 64) * 8]);
    }
  }
  f32x4 accO[8] = {};
  float mrow[4], lrow[4];
#pragma unroll
  for (int r = 0; r < 4; r++) { mrow[r] = -3.0e38f; lrow[r] = 0.f; }
  const int hk = h >> 2;
  const unsigned char* mptr = mask + ((long)h * 32 + qb) * 32;
  const float scale = 0.08838834764831845f;  // D^-0.5
  for (int kb = 0; kb <= qb; kb++) {
    if (!mptr[kb]) continue;
    __syncthreads();
    {
      const short* ks = k_bf + ((long)hk * S_LEN + (long)kb * 64) * HDIM;
#pragma unroll
      for (int i = 0; i < 4; i++) {
        int flat = tid + i * 256;
        gload16(ks + (long)flat * 8, &Ks[(i * 256 + wave * 64) * 8]);
      }
      const short* vsb = v_t + (long)hk * HDIM * S_LEN + (long)kb * 64;
#pragma unroll
      for (int i = 0; i < 4; i++) {
        int flat = tid + i * 256;
        int row = flat >> 3, off = (flat & 7) * 8;
        gload16(vsb + (long)row * S_LEN + off, &Vs[(i * 256 + wave * 64) * 8]);
      }
    }
    __syncthreads();
    // QK^T : per wave 16 q-rows x 64 k-cols
    f32x4 sc[4];
    {
      bf16x8 aq[4];
#pragma unroll
      for (int kd = 0; kd < 4; kd++)
        aq[kd] = *(const bf16x8*)&Qs[(wave * 16 + l15) * 128 + kd * 32 + quad * 8];
#pragma unroll
      for (int nt = 0; nt < 4; nt++) {
        f32x4 a = {};
#pragma unroll
        for (int kd = 0; kd < 4; kd++) {
          bf16x8 bk = *(const bf16x8*)&Ks[(nt * 16 + l15) * 128 + kd * 32 + quad * 8];
          a = __builtin_amdgcn_mfma_f32_16x16x32_bf16(aq[kd], bk, a, 0, 0, 0);
        }
        sc[nt] = a;
      }
    }
    // online softmax per row (row = quad*4 + r)
#pragma unroll
    for (int r = 0; r < 4; r++) {
      int qrow = quad * 4 + r;
      float sv[4];
#pragma unroll
      for (int nt = 0; nt < 4; nt++) {
        float x = sc[nt][r] * scale;
        if (kb == qb) {
          int kcol = nt * 16 + l15;
          if (kcol > (wave * 16 + qrow)) x = NEGF;
        }
        sv[nt] = x;
      }
      float mb = fmaxf(fmaxf(sv[0], sv[1]), fmaxf(sv[2], sv[3]));
#pragma unroll
      for (int off = 8; off > 0; off >>= 1) mb = fmaxf(mb, __shfl_xor(mb, off, 64));
      float mnew = fmaxf(mrow[r], mb);
      float alpha = __expf(mrow[r] - mnew);
      float psum = 0.f;
#pragma unroll
      for (int nt = 0; nt < 4; nt++) {
        float p = __expf(sv[nt] - mnew);
        psum += p;
        Ps[(wave * 16 + qrow) * 64 + nt * 16 + l15] = f2bf(p);
      }
#pragma unroll
      for (int off = 8; off > 0; off >>= 1) psum += __shfl_xor(psum, off, 64);
      lrow[r] = lrow[r] * alpha + psum;
      mrow[r] = mnew;
#pragma unroll
      for (int dt = 0; dt < 8; dt++) accO[dt][r] *= alpha;
    }
    // PV : P(16x64) @ V(64x128)
    {
      bf16x8 ap[2];
#pragma unroll
      for (int ksb = 0; ksb < 2; ksb++)
        ap[ksb] = *(const bf16x8*)&Ps[(wave * 16 + l15) * 64 + ksb * 32 + quad * 8];
#pragma unroll
      for (int dt = 0; dt < 8; dt++) {
#pragma unroll
        for (int ksb = 0; ksb < 2; ksb++) {
          bf16x8 bv = *(const bf16x8*)&Vs[(dt * 16 + l15) * 64 + ksb * 32 + quad * 8];
          accO[dt] = __builtin_amdgcn_mfma_f32_16x16x32_bf16(ap[ksb], bv, accO[dt], 0, 0, 0);
        }
      }
    }
  }
#pragma unroll
  for (int r = 0; r < 4; r++) {
    float inv = 1.f / lrow[r];
    long srow = (long)qb * 64 + wave * 16 + quad * 4 + r;
#pragma unroll
    for (int dt = 0; dt < 8; dt++)
      o_bf[srow * HIDN + h * HDIM + dt * 16 + l15] = f2bf(accO[dt][r] * inv);
  }
}

// ---------------- workspace layout ----------------
static constexpr size_t SZ_WQKVT = (size_t)NQKV * HIDN * 2;
static constexpr size_t SZ_WOT = (size_t)HIDN * HIDN * 2;
static constexpr size_t SZ_WBIG = (size_t)INTER * HIDN * 2;
static constexpr size_t OFF_WQKVT = 0;
static constexpr size_t OFF_WOT = OFF_WQKVT + SZ_WQKVT;
static constexpr size_t OFF_WGATET = OFF_WOT + SZ_WOT;
static constexpr size_t OFF_WUPT = OFF_WGATET + SZ_WBIG;
static constexpr size_t OFF_WDOWNT = OFF_WUPT + SZ_WBIG;
static constexpr size_t OFF_BIAS = OFF_WDOWNT + SZ_WBIG;
static constexpr size_t OFF_MASK = OFF_BIAS + 3072 * 4 + 4096;
static constexpr size_t OFF_QM = OFF_MASK + 16 * 32 * 32 + 4096;
static constexpr size_t OFF_KM = OFF_QM + (size_t)32 * 16 * 128 * 4;
static constexpr size_t OFF_QG = OFF_KM + (size_t)32 * 4 * 128 * 4;
static constexpr size_t OFF_KG = OFF_QG + (size_t)32 * 16 * 128 * 4;
static constexpr size_t OFF_H2 = OFF_KG + (size_t)32 * 4 * 128 * 4;
static constexpr size_t OFF_H3 = OFF_H2 + (size_t)S_LEN * HIDN * 4;
static constexpr size_t OFF_REGA = OFF_H3 + (size_t)S_LEN * HIDN * 2;
//   REGA phase1: h_bf | q_bf | k_bf | v_t | o_bf ; phase2: act_bf (o_bf dead)
static constexpr size_t RA_HBF = 0;
static constexpr size_t RA_QBF = RA_HBF + (size_t)S_LEN * HIDN * 2;
static constexpr size_t RA_KBF = RA_QBF + (size_t)HQ * S_LEN * HDIM * 2;
static constexpr size_t RA_VT = RA_KBF + (size_t)HKV * S_LEN * HDIM * 2;
static constexpr size_t RA_OBF = RA_VT + (size_t)HKV * HDIM * S_LEN * 2;
static constexpr size_t SZ_REGA = RA_OBF + (size_t)S_LEN * HIDN * 2;
static constexpr size_t OFF_REGB = OFF_REGA + SZ_REGA;
//   REGB phase1: qkv_f32 (S x 3072 f32) ; phase2: g_bf (S x INTER bf16)
static constexpr size_t SZ_REGB = (size_t)S_LEN * NQKV * 4;
static constexpr size_t TOTAL_WS = OFF_REGB + SZ_REGB;

extern "C" void kernel_launch(void* const* d_in, const int* in_sizes, int n_in,
                              void* d_out, int out_size, void* d_ws, size_t ws_size,
                              hipStream_t stream) {
  const float* hidden = (const float*)d_in[0];
  const float* cosb = (const float*)d_in[1];
  const float* sinb = (const float*)d_in[2];
  const float* ln1 = (const float*)d_in[3];
  const float* ln2 = (const float*)d_in[4];
  const float* Wq = (const float*)d_in[5];
  const float* bq = (const float*)d_in[6];
  const float* Wk = (const float*)d_in[7];
  const float* bk = (const float*)d_in[8];
  const float* Wv = (const float*)d_in[9];
  const float* bv = (const float*)d_in[10];
  const float* Wo = (const float*)d_in[11];
  const float* gWq = (const float*)d_in[12];
  const float* gWk = (const float*)d_in[13];
  const float* Wgate = (const float*)d_in[14];
  const float* Wup = (const float*)d_in[15];
  const float* Wdown = (const float*)d_in[16];

  if (ws_size < TOTAL_WS) return;  // workspace too small; fail visibly

  char* ws = (char*)d_ws;
  short* WqkvT = (short*)(ws + OFF_WQKVT);
  short* WoT = (short*)(ws + OFF_WOT);
  short* WgateT = (short*)(ws + OFF_WGATET);
  short* WupT = (short*)(ws + OFF_WUPT);
  short* WdownT = (short*)(ws + OFF_WDOWNT);
  float* biasqkv = (float*)(ws + OFF_BIAS);
  unsigned char* maskb = (unsigned char*)(ws + OFF_MASK);
  float* qm = (float*)(ws + OFF_QM);
  float* km = (float*)(ws + OFF_KM);
  float* qg = (float*)(ws + OFF_QG);
  float* kg = (float*)(ws + OFF_KG);
  float* h2 = (float*)(ws + OFF_H2);
  short* h3_bf = (short*)(ws + OFF_H3);
  short* h_bf = (short*)(ws + OFF_REGA + RA_HBF);
  short* q_bf = (short*)(ws + OFF_REGA + RA_QBF);
  short* k_bf = (short*)(ws + OFF_REGA + RA_KBF);
  short* v_t = (short*)(ws + OFF_REGA + RA_VT);
  short* o_bf = (short*)(ws + OFF_REGA + RA_OBF);
  short* act_bf = (short*)(ws + OFF_REGA);  // overlays h_bf..v_t (+part of o_bf), all dead by then
  float* qkv_f = (float*)(ws + OFF_REGB);
  short* g_bf = (short*)(ws + OFF_REGB);  // overlays qkv_f, dead by then
  float* outp = (float*)d_out;

  dim3 tb(32, 8);
  // weight transposes (fp32 -> bf16, N x K)
  k_transpose_cast<<<dim3(64, 64), tb, 0, stream>>>(Wq, WqkvT, HIDN, 2048);
  k_transpose_cast<<<dim3(16, 64), tb, 0, stream>>>(Wk, WqkvT + (size_t)2048 * HIDN, HIDN, 512);
  k_transpose_cast<<<dim3(16, 64), tb, 0, stream>>>(Wv, WqkvT + (size_t)2560 * HIDN, HIDN, 512);
  k_transpose_cast<<<dim3(64, 64), tb, 0, stream>>>(Wo, WoT, HIDN, HIDN);
  k_transpose_cast<<<dim3(176, 64), tb, 0, stream>>>(Wgate, WgateT, HIDN, INTER);
  k_transpose_cast<<<dim3(176, 64), tb, 0, stream>>>(Wup, WupT, HIDN, INTER);
  k_transpose_cast<<<dim3(64, 176), tb, 0, stream>>>(Wdown, WdownT, INTER, HIDN);
  k_bias_concat<<<12, 256, 0, stream>>>(bq, bk, bv, biasqkv);

  // h = RMS(hidden, ln1) -> bf16
  k_rms<<<S_LEN, 256, 0, stream>>>(hidden, ln1, h_bf);
  // qkv = h @ [Wq|Wk|Wv] + bias  (fp32)
  k_gemm<0><<<dim3(NQKV / 128, S_LEN / 128), 256, 0, stream>>>(
      h_bf, WqkvT, qkv_f, nullptr, biasqkv, nullptr, nullptr, S_LEN, NQKV, HIDN);
  // gate path (pre-RoPE q,k)
  k_blockmean<<<320, 256, 0, stream>>>(qkv_f, qm, km);
  k_gateproj<<<640, 128, 0, stream>>>(qm, km, gWq, gWk, qg, kg);
  k_gatemask<<<dim3(32, 16), 64, 0, stream>>>(qg, kg, maskb);
  // RoPE + layout change
  k_rope<<<10240, 256, 0, stream>>>(qkv_f, cosb, sinb, q_bf, k_bf);
  k_vcast<<<4096, 256, 0, stream>>>(qkv_f, v_t);
  // attention
  k_attn<<<dim3(32, 16), 256, 0, stream>>>(q_bf, k_bf, v_t, maskb, o_bf);
  // h2 = o @ Wo + hidden (fp32)
  k_gemm<0><<<dim3(16, 16), 256, 0, stream>>>(
      o_bf, WoT, h2, nullptr, nullptr, hidden, nullptr, S_LEN, HIDN, HIDN);
  // h3 = RMS(h2, ln2) -> bf16
  k_rms<<<S_LEN, 256, 0, stream>>>(h2, ln2, h3_bf);
  // g = h3 @ Wgate (bf16)
  k_gemm<1><<<dim3(INTER / 128, 16), 256, 0, stream>>>(
      h3_bf, WgateT, nullptr, g_bf, nullptr, nullptr, nullptr, S_LEN, INTER, HIDN);
  // act = silu(g) * (h3 @ Wup) (bf16)
  k_gemm<2><<<dim3(INTER / 128, 16), 256, 0, stream>>>(
      h3_bf, WupT, nullptr, act_bf, nullptr, nullptr, g_bf, S_LEN, INTER, HIDN);
  // out = act @ Wdown + h2 (fp32)
  k_gemm<0><<<dim3(16, 16), 256, 0, stream>>>(
      act_bf, WdownT, outp, nullptr, nullptr, h2, nullptr, S_LEN, HIDN, INTER);
  (void)in_sizes; (void)n_in; (void)out_size;
}